// Round 7
// baseline (695.990 us; speedup 1.0000x reference)
//
#include <hip/hip_runtime.h>
#include <cstdint>
#include <cstddef>

#define N_P 2048
#define N_W 89
#define N_ALLC 2137
#define BQ 16384
#define E2C 768

typedef __attribute__((ext_vector_type(8))) short short8;
typedef __attribute__((ext_vector_type(4))) float float4v;

// ---------------- helpers ----------------
__device__ __forceinline__ float waveMax(float v){
#pragma unroll
  for (int o = 32; o > 0; o >>= 1) v = fmaxf(v, __shfl_down(v, o, 64));
  return v;
}
__device__ __forceinline__ float waveSum(float v){
#pragma unroll
  for (int o = 32; o > 0; o >>= 1) v += __shfl_down(v, o, 64);
  return v;
}
__device__ __forceinline__ unsigned short f2bf(float f){
  union { float f; unsigned int u; } v; v.f = f;
  unsigned int u = v.u;
  unsigned int r = (u + 0x7FFFu + ((u >> 16) & 1u)) >> 16;
  return (unsigned short)r;
}
__device__ __forceinline__ short8 cvt8(const float* p){
  float4 f0 = *(const float4*)p;
  float4 f1 = *(const float4*)(p + 4);
  short8 a;
  a[0] = (short)f2bf(f0.x); a[1] = (short)f2bf(f0.y);
  a[2] = (short)f2bf(f0.z); a[3] = (short)f2bf(f0.w);
  a[4] = (short)f2bf(f1.x); a[5] = (short)f2bf(f1.y);
  a[6] = (short)f2bf(f1.z); a[7] = (short)f2bf(f1.w);
  return a;
}

// pack W[K][N] f32 -> bf16 MFMA B-fragment layout:
// out[((kb*4+q)*N + n)*8 + j] = bf16(W[(kb*32+q*8+j)*N + n])
__device__ __forceinline__ void wpk_one(const float* __restrict__ W,
                                        unsigned short* __restrict__ out,
                                        int K, int N, int idx){
  if (idx >= K * N) return;
  int k = idx / N, n = idx - k * N;
  out[((size_t)((k >> 5) * 4 + ((k >> 3) & 3)) * N + n) * 8 + (k & 7)] = f2bf(W[idx]);
}

// ---------------- one-shot init: all repacks + word copy + adjacency bitmasks ----------------
__global__ __launch_bounds__(256) void repack_all(
    const float* __restrict__ w1, float* __restrict__ wrm1,
    const float* __restrict__ w2, float* __restrict__ wrm2,
    const float* __restrict__ Ws1, unsigned short* __restrict__ ws1pk,
    const float* __restrict__ Ws2, unsigned short* __restrict__ ws2pk,
    const float* __restrict__ Wf1, unsigned short* __restrict__ wf1pk,
    const float* __restrict__ Wfa, unsigned short* __restrict__ wfapk,
    const float* __restrict__ wf, float* __restrict__ h1wp,
    const int* __restrict__ adj1, unsigned long long* __restrict__ bm1,
    const int* __restrict__ adj2, unsigned long long* __restrict__ bm2)
{
  int b = blockIdx.x, t = threadIdx.x;
  if (b < 256) {
    int idx = b * 256 + t;
    int f = idx >> 8, c = idx & 255;
    int h = c >> 5, o = c & 31;
    wrm1[idx] = w1[h * 8192 + f * 32 + o];
  } else if (b < 512) {
    int idx = (b - 256) * 256 + t;
    int f = idx >> 8, c = idx & 255;
    int h = c >> 5, o = c & 31;
    wrm2[idx] = w2[h * 8192 + f * 32 + o];
  } else if (b < 640) {
    wpk_one(Ws1, ws1pk, 256, 128, (b - 512) * 256 + t);
  } else if (b < 1024) {
    wpk_one(Ws2, ws2pk, 768, 128, (b - 640) * 256 + t);
  } else if (b < 1056) {
    wpk_one(Wf1, wf1pk, 128, 64, (b - 1024) * 256 + t);
  } else if (b < 1184) {
    wpk_one(Wfa, wfapk, 256, 128, (b - 1056) * 256 + t);
  } else if (b < 1273) {
    int idx = (b - 1184) * 256 + t;
    if (idx < N_W * 256) h1wp[idx] = wf[idx];
  } else if (b < 1529) {
    // adj1 -> bitmask [2048][32] u64, 8 rows per block
    int r0 = (b - 1273) * 8;
    int wv = t >> 6, ln = t & 63;
    for (int rr = 0; rr < 8; ++rr) {
      int r = r0 + rr;
      const int* arow = adj1 + (size_t)r * N_P;
      for (int m0 = wv * 64; m0 < N_P; m0 += 256) {
        unsigned long long mask = __ballot(arow[m0 + ln] > 0);
        if (ln == 0) bm1[(size_t)r * 32 + (m0 >> 6)] = mask;
      }
    }
  } else {
    // adj2 -> bitmask [2137][34] u64, 8 rows per block
    int r0 = (b - 1529) * 8;
    int wv = t >> 6, ln = t & 63;
    for (int rr = 0; rr < 8; ++rr) {
      int r = r0 + rr;
      if (r >= N_ALLC) break;
      const int* arow = adj2 + (size_t)r * N_ALLC;
      for (int m0 = wv * 64; m0 < 2176; m0 += 256) {
        int m = m0 + ln;
        unsigned long long mask = __ballot((m < N_ALLC) && (arow[m] > 0));
        if (ln == 0) bm2[(size_t)r * 34 + (m0 >> 6)] = mask;
      }
    }
  }
}

// ---------------- generic f32 GEMM (hp1 / hp2 only) ----------------
__global__ __launch_bounds__(256) void gemm_f32(
    const float* __restrict__ A, int lda,
    const float* __restrict__ B, int ldb,
    float* __restrict__ C, int ldc,
    int M, int N, int K)
{
  __shared__ __align__(16) float As[16][68];
  __shared__ __align__(16) float Bs[16][68];
  int t = threadIdx.x;
  int m0 = blockIdx.x * 64, n0 = blockIdx.y * 64;
  int tm = t >> 4, tn = t & 15;
  int ar = t >> 2, ak = (t & 3) * 4;
  int bk = t >> 4, bn = (t & 15) * 4;
  float acc[4][4] = {};
  for (int k0 = 0; k0 < K; k0 += 16) {
    float4 av = {0.f, 0.f, 0.f, 0.f};
    int arow = m0 + ar;
    if (arow < M) av = *(const float4*)(A + (size_t)arow * lda + k0 + ak);
    As[ak][ar] = av.x; As[ak + 1][ar] = av.y; As[ak + 2][ar] = av.z; As[ak + 3][ar] = av.w;
    *(float4*)&Bs[bk][bn] = *(const float4*)(B + (size_t)(k0 + bk) * ldb + n0 + bn);
    __syncthreads();
#pragma unroll
    for (int kk = 0; kk < 16; ++kk) {
      float4 a4 = *(const float4*)&As[kk][tm * 4];
      float4 b4 = *(const float4*)&Bs[kk][tn * 4];
      float a[4] = {a4.x, a4.y, a4.z, a4.w};
      float b[4] = {b4.x, b4.y, b4.z, b4.w};
#pragma unroll
      for (int i = 0; i < 4; ++i)
#pragma unroll
        for (int j = 0; j < 4; ++j) acc[i][j] += a[i] * b[j];
    }
    __syncthreads();
  }
#pragma unroll
  for (int i = 0; i < 4; ++i) {
    int row = m0 + tm * 4 + i;
    if (row < M) {
      float4 v;
      v.x = acc[i][0]; v.y = acc[i][1]; v.z = acc[i][2]; v.w = acc[i][3];
      *(float4*)(C + (size_t)row * ldc + n0 + tn * 4) = v;
    }
  }
}

// ---------------- e_src / e_dst (+ optional hp bf16 pack, + optional h2w init) ----------------
__global__ __launch_bounds__(256) void esrc_edst(
    const float* __restrict__ hp,
    const float* __restrict__ a_src,
    const float* __restrict__ a_dst,
    float* __restrict__ es, float* __restrict__ ed,
    unsigned short* __restrict__ hppk,          // pack dst (do_pack=1)
    float* __restrict__ h2w, const float* __restrict__ b2,  // optional init
    int N, int do_pack)
{
  __shared__ float sa[256], sd[256];
  int t = threadIdx.x;
  sa[t] = a_src[t]; sd[t] = a_dst[t];
  __syncthreads();
  int idx = blockIdx.x * 256 + t;
  if (h2w != nullptr && idx < N_W * 32) h2w[idx] = b2[idx & 31];
  if (idx >= N * 8) return;
  int n = idx >> 3, h = idx & 7;
  const float* hpp = hp + (size_t)n * 256 + h * 32;
  const float* ap = sa + h * 32;
  const float* dp = sd + h * 32;
  float s = 0.f, d = 0.f;
  float hv[32];
#pragma unroll
  for (int o = 0; o < 32; ++o) { hv[o] = hpp[o]; s += hv[o] * ap[o]; d += hv[o] * dp[o]; }
  es[h * N + n] = s; ed[h * N + n] = d;
  if (do_pack) {
    // B-fragment pack for pv1: element (k=n, col=o), head h
    unsigned short* dst = hppk + (size_t)h * (N_P * 32)
                        + (size_t)((n >> 5) * 4 + ((n >> 3) & 3)) * 256 + (n & 7);
#pragma unroll
    for (int o = 0; o < 32; ++o) dst[o * 8] = f2bf(hv[o]);
  }
}

// ---------------- attention softmax (GAT2 only): one block per (head,row), bitmask adjacency ----------------
__global__ __launch_bounds__(256) void attn_softmax(
    const float* __restrict__ es, const float* __restrict__ ed,
    const unsigned long long* __restrict__ bm, int bstride,
    float* __restrict__ attn,
    int N)
{
  int h = blockIdx.x, n = blockIdx.y;
  int t = threadIdx.x, lane = t & 63, wid = t >> 6;
  __shared__ float red[4];
  float esv = es[h * N + n];
  const float* edh = ed + (size_t)h * N;
  const unsigned long long* brow = bm + (size_t)n * bstride;
  float v[9];
  float lmax = -3e38f;
#pragma unroll
  for (int i = 0; i < 9; ++i) {
    int m = i * 256 + t;
    float x = -3e38f;
    if (m < N) {
      float e = esv + edh[m];
      e = (e >= 0.f) ? e : 0.2f * e;
      x = ((brow[m >> 6] >> (m & 63)) & 1ULL) ? e : -1e9f;
    }
    v[i] = x; lmax = fmaxf(lmax, x);
  }
  lmax = waveMax(lmax);
  if (lane == 0) red[wid] = lmax;
  __syncthreads();
  float gmax = fmaxf(fmaxf(red[0], red[1]), fmaxf(red[2], red[3]));
  __syncthreads();
  float lsum = 0.f;
#pragma unroll
  for (int i = 0; i < 9; ++i) {
    int m = i * 256 + t;
    if (m < N) { float p = __expf(v[i] - gmax); v[i] = p; lsum += p; }
  }
  lsum = waveSum(lsum);
  if (lane == 0) red[wid] = lsum;
  __syncthreads();
  float inv = 1.f / (red[0] + red[1] + red[2] + red[3]);
  float* out = attn + ((size_t)h * N + n) * N;
#pragma unroll
  for (int i = 0; i < 9; ++i) {
    int m = i * 256 + t;
    if (m < N) out[m] = v[i] * inv;
  }
}

// ---------------- fused GAT1 softmax + PV (bf16 MFMA) + bias + elu ----------------
// grid (64, 8): 32 rows per block, head = blockIdx.y. Waves: w = kh*2 + rhs.
// Pass A: two L2-resident sweeps compute per-row max and sum (kh-half partials, LDS-combined).
// Pass B: recompute P in registers, write f32 attn (required output), feed bf16 MFMA PV.
__global__ __launch_bounds__(256) void sm_pv1(
    const float* __restrict__ es, const float* __restrict__ ed,
    const unsigned long long* __restrict__ bm,   // [2048][32]
    const unsigned short* __restrict__ hppk,     // [8][2048*32] packed bf16
    const float* __restrict__ bias,              // [32]
    float* __restrict__ attn,                    // out [8][2048][2048]
    float* __restrict__ h1wp)                    // rows 89..
{
  __shared__ float pmax[2][32];
  __shared__ float psum[2][32];
  __shared__ float sM[32], sInv[32];
  __shared__ float red[2][16][33];
  int t = threadIdx.x, w = t >> 6, lane = t & 63;
  int col = lane & 15, quad = lane >> 4;
  int kh = w >> 1, rhs = w & 1;
  int h = blockIdx.y;
  int row0 = blockIdx.x * 32;
  const float* edh = ed + (size_t)h * N_P + kh * 1024;

  // ---- sweep 1: per-row partial max over this wave's K-half ----
  for (int r = 0; r < 16; ++r) {
    int n = row0 + rhs * 16 + r;
    float esv = es[h * N_P + n];
    const unsigned long long* brow = bm + (size_t)n * 32 + kh * 16;
    float lmax = -3e38f;
#pragma unroll 4
    for (int s = 0; s < 16; ++s) {
      unsigned long long mk = brow[s];
      float e = esv + edh[s * 64 + lane];
      e = (e >= 0.f) ? e : 0.2f * e;
      float x = ((mk >> lane) & 1ULL) ? e : -1e9f;
      lmax = fmaxf(lmax, x);
    }
    lmax = waveMax(lmax);
    if (lane == 0) pmax[kh][rhs * 16 + r] = lmax;
  }
  __syncthreads();
  if (t < 32) sM[t] = fmaxf(pmax[0][t], pmax[1][t]);
  __syncthreads();

  // ---- sweep 2: per-row partial sum of exp(x - M) ----
  for (int r = 0; r < 16; ++r) {
    int n = row0 + rhs * 16 + r;
    float esv = es[h * N_P + n];
    float M = sM[rhs * 16 + r];
    const unsigned long long* brow = bm + (size_t)n * 32 + kh * 16;
    float lsum = 0.f;
#pragma unroll 4
    for (int s = 0; s < 16; ++s) {
      unsigned long long mk = brow[s];
      float e = esv + edh[s * 64 + lane];
      e = (e >= 0.f) ? e : 0.2f * e;
      float x = ((mk >> lane) & 1ULL) ? e : -1e9f;
      lsum += __expf(x - M);
    }
    lsum = waveSum(lsum);
    if (lane == 0) psum[kh][rhs * 16 + r] = lsum;
  }
  __syncthreads();
  if (t < 32) sInv[t] = 1.f / (psum[0][t] + psum[1][t]);
  __syncthreads();

  // ---- pass B: emit attn + MFMA PV (A-fragment row = col, k = quad*8+j) ----
  int nrow = row0 + rhs * 16 + col;
  float esv = es[h * N_P + nrow];
  float M = sM[rhs * 16 + col];
  float inv = sInv[rhs * 16 + col];
  const unsigned long long* brow = bm + (size_t)nrow * 32;
  float* arow = attn + ((size_t)h * N_P + nrow) * N_P + kh * 1024;
  const float* edq = edh + quad * 8;
  const unsigned short* wb0 = hppk + (size_t)h * (N_P * 32) + (size_t)kh * 32768;
  float4v acc0 = {0.f, 0.f, 0.f, 0.f}, acc1 = {0.f, 0.f, 0.f, 0.f};
#pragma unroll 4
  for (int kk = 0; kk < 1024; kk += 32) {
    int kc = kk + quad * 8;                      // offset within this K-half
    unsigned long long mw = brow[(kh * 1024 + kc) >> 6];
    int sh = (kk & 63) + quad * 8;               // bit offset (no carry: <= 56)
    float4 e0 = *(const float4*)(edq + kk);
    float4 e1 = *(const float4*)(edq + kk + 4);
    float ev[8] = {e0.x, e0.y, e0.z, e0.w, e1.x, e1.y, e1.z, e1.w};
    float p[8];
#pragma unroll
    for (int j = 0; j < 8; ++j) {
      float e = esv + ev[j];
      e = (e >= 0.f) ? e : 0.2f * e;
      float x = ((mw >> (sh + j)) & 1ULL) ? e : -1e9f;
      p[j] = __expf(x - M) * inv;
    }
    float4 o0 = {p[0], p[1], p[2], p[3]};
    float4 o1 = {p[4], p[5], p[6], p[7]};
    *(float4*)(arow + kc) = o0;
    *(float4*)(arow + kc + 4) = o1;
    short8 a;
#pragma unroll
    for (int j = 0; j < 8; ++j) a[j] = (short)f2bf(p[j]);
    const unsigned short* wb = wb0 + ((size_t)((kk >> 5) * 4 + quad) * 32 + col) * 8;
    short8 b0 = *(const short8*)(wb);
    short8 b1 = *(const short8*)(wb + 128);
    acc0 = __builtin_amdgcn_mfma_f32_16x16x32_bf16(a, b0, acc0, 0, 0, 0);
    acc1 = __builtin_amdgcn_mfma_f32_16x16x32_bf16(a, b1, acc1, 0, 0, 0);
  }
  // ---- combine K-halves + epilogue (identical to pv1_mfma) ----
  if (kh == 1) {
#pragma unroll
    for (int r = 0; r < 4; ++r) {
      red[rhs][quad * 4 + r][col] = acc0[r];
      red[rhs][quad * 4 + r][16 + col] = acc1[r];
    }
  }
  __syncthreads();
  if (kh == 0) {
    int rbase = row0 + rhs * 16 + quad * 4;
#pragma unroll
    for (int r = 0; r < 4; ++r) {
      float v0 = acc0[r] + red[rhs][quad * 4 + r][col] + bias[col];
      float v1 = acc1[r] + red[rhs][quad * 4 + r][16 + col] + bias[16 + col];
      v0 = (v0 > 0.f) ? v0 : expm1f(v0);
      v1 = (v1 > 0.f) ? v1 : expm1f(v1);
      float* dst = h1wp + (size_t)(N_W + rbase + r) * 256 + h * 32;
      dst[col] = v0; dst[16 + col] = v1;
    }
  }
}

// ---------------- PV for GAT2 word rows (h2w pre-initialized with bias) ----------------
__global__ __launch_bounds__(256) void pv2(
    const float* __restrict__ attn,
    const float* __restrict__ hp,
    float* __restrict__ h2w)
{
  int n = blockIdx.x, h = blockIdx.y;
  int t = threadIdx.x, g = t >> 5, o = t & 31;
  const float* arow = attn + ((size_t)h * N_ALLC + n) * N_ALLC;
  float acc = 0.f;
  for (int m = g; m < N_ALLC; m += 8) acc += arow[m] * hp[(size_t)m * 256 + h * 32 + o];
  __shared__ float pv[8][33];
  pv[g][o] = acc;
  __syncthreads();
  if (t < 32) {
    float s = 0.f;
#pragma unroll
    for (int gg = 0; gg < 8; ++gg) s += pv[gg][t];
    atomicAdd(&h2w[n * 32 + t], s * 0.125f);
  }
}

// ---------------- x: head matmul + concat + row-normalize (full-256-thread dot) ----------------
__global__ __launch_bounds__(256) void xnorm_kernel(
    const float* __restrict__ uwa,
    const float* __restrict__ h2w,
    float* __restrict__ xout)
{
  __shared__ float urow[4][320];
  __shared__ float sh2w[N_W * 32];
  __shared__ float px[4][2][32];
  __shared__ float xh[4][33];
  __shared__ float inv[4];
  int t = threadIdx.x;
  int b0 = blockIdx.x * 4;
  for (int i = t; i < N_W * 32; i += 256) sh2w[i] = h2w[i];
  for (int idx = t; idx < 4 * 313; idx += 256) {
    int r = idx / 313, j = idx - r * 313;
    urow[r][j] = uwa[(size_t)(b0 + r) * 313 + j];
  }
  __syncthreads();
  {
    int r = t >> 6, q = (t >> 5) & 1, o = t & 31;
    float s = 0.f;
    int i0 = q * 45, i1 = q ? N_W : 45;
    for (int i = i0; i < i1; ++i) s += urow[r][i] * sh2w[i * 32 + o];
    px[r][q][o] = s;
  }
  __syncthreads();
  if (t < 128) {
    int r = t >> 5, o = t & 31;
    xh[r][o] = px[r][0][o] + px[r][1][o];
  }
  __syncthreads();
  int lane = t & 63, w = t >> 6;
  float ls = 0.f;
  for (int c = lane; c < 256; c += 64) {
    float v = (c < 32) ? xh[w][c] : urow[w][89 + c - 32];
    ls += v;
  }
  ls = waveSum(ls);
  if (lane == 0) inv[w] = 1.f / ls;
  __syncthreads();
  for (int idx = t; idx < 1024; idx += 256) {
    int r = idx >> 8, c = idx & 255;
    float v = (c < 32) ? xh[r][c] : urow[r][89 + c - 32];
    xout[(size_t)(b0 + r) * 256 + c] = v * inv[r];
  }
}

// ---------------- fused o1|o2 -> o12bf (bf16 row-major [B][256]) ----------------
// grid (BQ/64, 2): y==0 -> o1 = x@Ws1+bs1 (cols 0..127); y==1 -> o2 = sent@Ws2+bs2 (cols 128..255)
__global__ __launch_bounds__(256) void o12_fused(
    const float* __restrict__ x,
    const float* __restrict__ sent,
    const unsigned short* __restrict__ ws1pk,
    const unsigned short* __restrict__ ws2pk,
    const float* __restrict__ bs1,
    const float* __restrict__ bs2,
    unsigned short* __restrict__ o12bf)
{
  int t = threadIdx.x, w = t >> 6, lane = t & 63;
  int col = lane & 15, quad = lane >> 4;
  int rowA = blockIdx.x * 64 + w * 16 + col;
  int half = blockIdx.y;
  const float* A = half ? (sent + (size_t)rowA * E2C) : (x + (size_t)rowA * 256);
  const unsigned short* wpk = half ? ws2pk : ws1pk;
  const float* bias = half ? bs2 : bs1;
  int K = half ? E2C : 256;
  float4v acc[8];
#pragma unroll
  for (int i = 0; i < 8; ++i) acc[i] = (float4v){0.f, 0.f, 0.f, 0.f};
#pragma unroll 4
  for (int k0 = 0; k0 < K; k0 += 32) {
    short8 a = cvt8(A + k0 + quad * 8);
    const unsigned short* wb = wpk + ((size_t)((k0 >> 5) * 4 + quad) * 128 + col) * 8;
#pragma unroll
    for (int nt = 0; nt < 8; ++nt)
      acc[nt] = __builtin_amdgcn_mfma_f32_16x16x32_bf16(a, *(const short8*)(wb + nt * 128), acc[nt], 0, 0, 0);
  }
  int rbase = blockIdx.x * 64 + w * 16 + quad * 4;
  int cb = half * 128;
#pragma unroll
  for (int nt = 0; nt < 8; ++nt) {
    int c = nt * 16 + col;
    float bv = bias[c];
#pragma unroll
    for (int r = 0; r < 4; ++r)
      o12bf[(size_t)(rbase + r) * 256 + cb + c] = f2bf(acc[nt][r] + bv);
  }
}

// ---------------- fused tail: o1n, o2n, t=relu(o12@Wfa+bfa), xtemp=t@Wfb+bfb ----------------
__global__ __launch_bounds__(256) void tail_fused(
    const unsigned short* __restrict__ o12bf,
    const unsigned short* __restrict__ wf1pk,   // K=128, N=64
    const unsigned short* __restrict__ wfapk,   // K=256, N=128
    const float* __restrict__ bf1,
    const float* __restrict__ bfa,
    const float* __restrict__ Wfb,              // [128][5]
    const float* __restrict__ bfb,              // [5]
    float* __restrict__ o1n, float* __restrict__ o2n, float* __restrict__ xt)
{
  __shared__ float sWfb[640];
  int t = threadIdx.x;
  for (int i = t; i < 640; i += 256) sWfb[i] = Wfb[i];
  __syncthreads();
  int w = t >> 6, lane = t & 63;
  int col = lane & 15, quad = lane >> 4;
  int rowA = blockIdx.x * 64 + w * 16 + col;
  const unsigned short* ar = o12bf + (size_t)rowA * 256;
  float4v aT[8], a1[4], a2[4];
#pragma unroll
  for (int i = 0; i < 8; ++i) aT[i] = (float4v){0.f, 0.f, 0.f, 0.f};
#pragma unroll
  for (int i = 0; i < 4; ++i) { a1[i] = (float4v){0.f, 0.f, 0.f, 0.f}; a2[i] = (float4v){0.f, 0.f, 0.f, 0.f}; }
#pragma unroll
  for (int k0 = 0; k0 < 128; k0 += 32) {
    short8 a = *(const short8*)(ar + k0 + quad * 8);
    const unsigned short* wbT = wfapk + ((size_t)((k0 >> 5) * 4 + quad) * 128 + col) * 8;
    const unsigned short* wb1 = wf1pk + ((size_t)((k0 >> 5) * 4 + quad) * 64 + col) * 8;
#pragma unroll
    for (int nt = 0; nt < 8; ++nt)
      aT[nt] = __builtin_amdgcn_mfma_f32_16x16x32_bf16(a, *(const short8*)(wbT + nt * 128), aT[nt], 0, 0, 0);
#pragma unroll
    for (int nt = 0; nt < 4; ++nt)
      a1[nt] = __builtin_amdgcn_mfma_f32_16x16x32_bf16(a, *(const short8*)(wb1 + nt * 128), a1[nt], 0, 0, 0);
  }
#pragma unroll
  for (int k0 = 128; k0 < 256; k0 += 32) {
    short8 a = *(const short8*)(ar + k0 + quad * 8);
    const unsigned short* wbT = wfapk + ((size_t)((k0 >> 5) * 4 + quad) * 128 + col) * 8;
    const unsigned short* wb1 = wf1pk + ((size_t)(((k0 - 128) >> 5) * 4 + quad) * 64 + col) * 8;
#pragma unroll
    for (int nt = 0; nt < 8; ++nt)
      aT[nt] = __builtin_amdgcn_mfma_f32_16x16x32_bf16(a, *(const short8*)(wbT + nt * 128), aT[nt], 0, 0, 0);
#pragma unroll
    for (int nt = 0; nt < 4; ++nt)
      a2[nt] = __builtin_amdgcn_mfma_f32_16x16x32_bf16(a, *(const short8*)(wb1 + nt * 128), a2[nt], 0, 0, 0);
  }
  int rbase = blockIdx.x * 64 + w * 16 + quad * 4;
#pragma unroll
  for (int nt = 0; nt < 4; ++nt) {
    int c = nt * 16 + col;
    float b1v = bf1[c];
#pragma unroll
    for (int r = 0; r < 4; ++r) {
      o1n[(size_t)(rbase + r) * 64 + c] = a1[nt][r] + b1v;
      o2n[(size_t)(rbase + r) * 64 + c] = a2[nt][r] + b1v;
    }
  }
  float xp[4][5] = {};
#pragma unroll
  for (int nt = 0; nt < 8; ++nt) {
    int c = nt * 16 + col;
    float bav = bfa[c];
#pragma unroll
    for (int r = 0; r < 4; ++r) {
      float tv = fmaxf(aT[nt][r] + bav, 0.f);
#pragma unroll
      for (int q = 0; q < 5; ++q) xp[r][q] += tv * sWfb[c * 5 + q];
    }
  }
#pragma unroll
  for (int m = 1; m <= 8; m <<= 1) {
#pragma unroll
    for (int r = 0; r < 4; ++r)
#pragma unroll
      for (int q = 0; q < 5; ++q) xp[r][q] += __shfl_xor(xp[r][q], m, 64);
  }
  if (col == 0) {
#pragma unroll
    for (int r = 0; r < 4; ++r)
#pragma unroll
      for (int q = 0; q < 5; ++q) xt[(size_t)(rbase + r) * 5 + q] = xp[r][q] + bfb[q];
  }
}

extern "C" void kernel_launch(void* const* d_in, const int* in_sizes, int n_in,
                              void* d_out, int out_size, void* d_ws, size_t ws_size,
                              hipStream_t stream)
{
  const float* pf   = (const float*)d_in[0];
  const float* wf   = (const float*)d_in[1];
  const int*   adj1 = (const int*)d_in[2];
  const int*   adj2 = (const int*)d_in[3];
  const float* uwa  = (const float*)d_in[4];
  const float* sent = (const float*)d_in[5];
  const float* w1   = (const float*)d_in[6];
  const float* as1  = (const float*)d_in[7];
  const float* ad1  = (const float*)d_in[8];
  const float* b1   = (const float*)d_in[9];
  const float* w2   = (const float*)d_in[10];
  const float* as2  = (const float*)d_in[11];
  const float* ad2  = (const float*)d_in[12];
  const float* b2   = (const float*)d_in[13];
  const float* Ws1  = (const float*)d_in[14];
  const float* bs1  = (const float*)d_in[15];
  const float* Ws2  = (const float*)d_in[16];
  const float* bs2  = (const float*)d_in[17];
  const float* Wf1  = (const float*)d_in[18];
  const float* bf1  = (const float*)d_in[19];
  const float* Wfa  = (const float*)d_in[20];
  const float* bfa  = (const float*)d_in[21];
  const float* Wfb  = (const float*)d_in[22];
  const float* bfb  = (const float*)d_in[23];

  float* ws = (float*)d_ws;
  float* wrm1 = ws;                                   // 65536
  float* wrm2 = wrm1 + 65536;                         // 65536
  float* hp1  = wrm2 + 65536;                         // 2048*256
  float* hp2  = hp1 + (size_t)N_P * 256;              // 2137*256
  float* es1v = hp2 + (size_t)N_ALLC * 256;           // 16384
  float* ed1v = es1v + 8 * N_P;                       // 16384
  float* es2v = ed1v + 8 * N_P;                       // 17096 (pad 17152)
  float* ed2v = es2v + 17152;                         // 17096 (pad 17152)
  float* h1wp = ed2v + 17152;                         // 2137*256
  float* h2w  = h1wp + (size_t)N_ALLC * 256;          // 2848 (pad 2880)
  unsigned long long* bm1 = (unsigned long long*)(h2w + 2880);  // 2048*32 u64
  unsigned long long* bm2 = bm1 + (size_t)2048 * 32;            // 2137*34 u64 (pad 72704)
  unsigned short* o12bf = (unsigned short*)(bm2 + 72704);       // BQ*256 ushorts
  unsigned short* hp1pk = o12bf + (size_t)BQ * 256;             // 8*2048*32
  unsigned short* ws1pk = hp1pk + 8 * N_P * 32;                 // 256*128
  unsigned short* ws2pk = ws1pk + 256 * 128;                    // 768*128
  unsigned short* wf1pk = ws2pk + 768 * 128;                    // 128*64
  unsigned short* wfapk = wf1pk + 128 * 64;                     // 256*128

  float* out = (float*)d_out;
  float* out_o1n = out;                                   // [B][64]
  float* out_o2n = out + (size_t)BQ * 64;                 // [B][64]
  float* out_xt  = out + (size_t)BQ * 128;                // [B][5]
  float* out_app = out_xt + (size_t)BQ * 5;               // [8][2048][2048]
  float* out_awp = out_app + (size_t)8 * N_P * N_P;       // [8][2137][2137]
  float* out_x   = out_awp + (size_t)8 * N_ALLC * N_ALLC; // [B][256]

  // 1. all repacks + word copy + adjacency bitmasks
  repack_all<<<1797, 256, 0, stream>>>(w1, wrm1, w2, wrm2, Ws1, ws1pk, Ws2, ws2pk,
                                       Wf1, wf1pk, Wfa, wfapk, wf, h1wp,
                                       adj1, bm1, adj2, bm2);
  // 2. hp1 = pern_feature @ W1rm
  gemm_f32<<<dim3(32, 4), 256, 0, stream>>>(pf, 256, wrm1, 256, hp1, 256, N_P, 256, 256);
  // 3. e_src/e_dst GAT1 + bf16 pack of hp1
  esrc_edst<<<(N_P * 8 + 255) / 256, 256, 0, stream>>>(hp1, as1, ad1, es1v, ed1v,
                                                       hp1pk, nullptr, nullptr, N_P, 1);
  // 4. fused GAT1 softmax + PV + bias + elu -> out_app, h1wp rows 89..
  sm_pv1<<<dim3(64, 8), 256, 0, stream>>>(es1v, ed1v, bm1, hp1pk, b1, out_app, h1wp);
  // 5. hp2 = h1wp @ W2rm
  gemm_f32<<<dim3(34, 4), 256, 0, stream>>>(h1wp, 256, wrm2, 256, hp2, 256, N_ALLC, 256, 256);
  // 6. e_src/e_dst GAT2 (+ h2w bias init)
  esrc_edst<<<(N_ALLC * 8 + 255) / 256, 256, 0, stream>>>(hp2, as2, ad2, es2v, ed2v,
                                                          nullptr, h2w, b2, N_ALLC, 0);
  // 7. attn softmax GAT2 -> out_awp
  attn_softmax<<<dim3(8, N_ALLC), 256, 0, stream>>>(es2v, ed2v, bm2, 34, out_awp, N_ALLC);
  // 8. PV2 word rows -> h2w (atomic mean)
  pv2<<<dim3(N_W, 8), 256, 0, stream>>>(out_awp, hp2, h2w);
  // 9. x = normalize(cat(uwa[:, :89]@h2w, uwa[:, 89:])) -> out_x
  xnorm_kernel<<<BQ / 4, 256, 0, stream>>>(uwa, h2w, out_x);
  // 10. o12bf = bf16(cat(x@Ws1+bs1, sent@Ws2+bs2))
  o12_fused<<<dim3(BQ / 64, 2), 256, 0, stream>>>(out_x, sent, ws1pk, ws2pk, bs1, bs2, o12bf);
  // 11. o1n, o2n, xtemp
  tail_fused<<<BQ / 64, 256, 0, stream>>>(o12bf, wf1pk, wfapk, bf1, bfa, Wfb, bfb,
                                          out_o1n, out_o2n, out_xt);
}

// Round 8
// 680.024 us; speedup vs baseline: 1.0235x; 1.0235x over previous
//
#include <hip/hip_runtime.h>
#include <cstdint>
#include <cstddef>

#define N_P 2048
#define N_W 89
#define N_ALLC 2137
#define BQ 16384
#define E2C 768

typedef __attribute__((ext_vector_type(8))) short short8;
typedef __attribute__((ext_vector_type(4))) float float4v;

// ---------------- helpers ----------------
__device__ __forceinline__ float waveMax(float v){
#pragma unroll
  for (int o = 32; o > 0; o >>= 1) v = fmaxf(v, __shfl_down(v, o, 64));
  return v;
}
__device__ __forceinline__ float waveSum(float v){
#pragma unroll
  for (int o = 32; o > 0; o >>= 1) v += __shfl_down(v, o, 64);
  return v;
}
__device__ __forceinline__ unsigned short f2bf(float f){
  union { float f; unsigned int u; } v; v.f = f;
  unsigned int u = v.u;
  unsigned int r = (u + 0x7FFFu + ((u >> 16) & 1u)) >> 16;
  return (unsigned short)r;
}
__device__ __forceinline__ short8 cvt8(const float* p){
  float4 f0 = *(const float4*)p;
  float4 f1 = *(const float4*)(p + 4);
  short8 a;
  a[0] = (short)f2bf(f0.x); a[1] = (short)f2bf(f0.y);
  a[2] = (short)f2bf(f0.z); a[3] = (short)f2bf(f0.w);
  a[4] = (short)f2bf(f1.x); a[5] = (short)f2bf(f1.y);
  a[6] = (short)f2bf(f1.z); a[7] = (short)f2bf(f1.w);
  return a;
}

// pack W[K][N] f32 -> bf16 MFMA B-fragment layout:
// out[((kb*4+q)*N + n)*8 + j] = bf16(W[(kb*32+q*8+j)*N + n])
__device__ __forceinline__ void wpk_one(const float* __restrict__ W,
                                        unsigned short* __restrict__ out,
                                        int K, int N, int idx){
  if (idx >= K * N) return;
  int k = idx / N, n = idx - k * N;
  out[((size_t)((k >> 5) * 4 + ((k >> 3) & 3)) * N + n) * 8 + (k & 7)] = f2bf(W[idx]);
}

// ---------------- one-shot init: all repacks + word copy + adjacency bitmasks ----------------
__global__ __launch_bounds__(256) void repack_all(
    const float* __restrict__ w1, float* __restrict__ wrm1,
    const float* __restrict__ w2, float* __restrict__ wrm2,
    const float* __restrict__ Ws1, unsigned short* __restrict__ ws1pk,
    const float* __restrict__ Ws2, unsigned short* __restrict__ ws2pk,
    const float* __restrict__ Wf1, unsigned short* __restrict__ wf1pk,
    const float* __restrict__ Wfa, unsigned short* __restrict__ wfapk,
    const float* __restrict__ wf, float* __restrict__ h1wp,
    const int* __restrict__ adj1, unsigned long long* __restrict__ bm1,
    const int* __restrict__ adj2, unsigned long long* __restrict__ bm2)
{
  int b = blockIdx.x, t = threadIdx.x;
  if (b < 256) {
    int idx = b * 256 + t;
    int f = idx >> 8, c = idx & 255;
    int h = c >> 5, o = c & 31;
    wrm1[idx] = w1[h * 8192 + f * 32 + o];
  } else if (b < 512) {
    int idx = (b - 256) * 256 + t;
    int f = idx >> 8, c = idx & 255;
    int h = c >> 5, o = c & 31;
    wrm2[idx] = w2[h * 8192 + f * 32 + o];
  } else if (b < 640) {
    wpk_one(Ws1, ws1pk, 256, 128, (b - 512) * 256 + t);
  } else if (b < 1024) {
    wpk_one(Ws2, ws2pk, 768, 128, (b - 640) * 256 + t);
  } else if (b < 1056) {
    wpk_one(Wf1, wf1pk, 128, 64, (b - 1024) * 256 + t);
  } else if (b < 1184) {
    wpk_one(Wfa, wfapk, 256, 128, (b - 1056) * 256 + t);
  } else if (b < 1273) {
    int idx = (b - 1184) * 256 + t;
    if (idx < N_W * 256) h1wp[idx] = wf[idx];
  } else if (b < 1529) {
    // adj1 -> bitmask [2048][32] u64, 8 rows per block
    int r0 = (b - 1273) * 8;
    int wv = t >> 6, ln = t & 63;
    for (int rr = 0; rr < 8; ++rr) {
      int r = r0 + rr;
      const int* arow = adj1 + (size_t)r * N_P;
      for (int m0 = wv * 64; m0 < N_P; m0 += 256) {
        unsigned long long mask = __ballot(arow[m0 + ln] > 0);
        if (ln == 0) bm1[(size_t)r * 32 + (m0 >> 6)] = mask;
      }
    }
  } else {
    // adj2 -> bitmask [2137][34] u64, 8 rows per block
    int r0 = (b - 1529) * 8;
    int wv = t >> 6, ln = t & 63;
    for (int rr = 0; rr < 8; ++rr) {
      int r = r0 + rr;
      if (r >= N_ALLC) break;
      const int* arow = adj2 + (size_t)r * N_ALLC;
      for (int m0 = wv * 64; m0 < 2176; m0 += 256) {
        int m = m0 + ln;
        unsigned long long mask = __ballot((m < N_ALLC) && (arow[m] > 0));
        if (ln == 0) bm2[(size_t)r * 34 + (m0 >> 6)] = mask;
      }
    }
  }
}

// ---------------- generic f32 GEMM (hp1 / hp2 only) ----------------
__global__ __launch_bounds__(256) void gemm_f32(
    const float* __restrict__ A, int lda,
    const float* __restrict__ B, int ldb,
    float* __restrict__ C, int ldc,
    int M, int N, int K)
{
  __shared__ __align__(16) float As[16][68];
  __shared__ __align__(16) float Bs[16][68];
  int t = threadIdx.x;
  int m0 = blockIdx.x * 64, n0 = blockIdx.y * 64;
  int tm = t >> 4, tn = t & 15;
  int ar = t >> 2, ak = (t & 3) * 4;
  int bk = t >> 4, bn = (t & 15) * 4;
  float acc[4][4] = {};
  for (int k0 = 0; k0 < K; k0 += 16) {
    float4 av = {0.f, 0.f, 0.f, 0.f};
    int arow = m0 + ar;
    if (arow < M) av = *(const float4*)(A + (size_t)arow * lda + k0 + ak);
    As[ak][ar] = av.x; As[ak + 1][ar] = av.y; As[ak + 2][ar] = av.z; As[ak + 3][ar] = av.w;
    *(float4*)&Bs[bk][bn] = *(const float4*)(B + (size_t)(k0 + bk) * ldb + n0 + bn);
    __syncthreads();
#pragma unroll
    for (int kk = 0; kk < 16; ++kk) {
      float4 a4 = *(const float4*)&As[kk][tm * 4];
      float4 b4 = *(const float4*)&Bs[kk][tn * 4];
      float a[4] = {a4.x, a4.y, a4.z, a4.w};
      float b[4] = {b4.x, b4.y, b4.z, b4.w};
#pragma unroll
      for (int i = 0; i < 4; ++i)
#pragma unroll
        for (int j = 0; j < 4; ++j) acc[i][j] += a[i] * b[j];
    }
    __syncthreads();
  }
#pragma unroll
  for (int i = 0; i < 4; ++i) {
    int row = m0 + tm * 4 + i;
    if (row < M) {
      float4 v;
      v.x = acc[i][0]; v.y = acc[i][1]; v.z = acc[i][2]; v.w = acc[i][3];
      *(float4*)(C + (size_t)row * ldc + n0 + tn * 4) = v;
    }
  }
}

// ---------------- e_src / e_dst (+ optional hp bf16 pack, + optional h2w init) ----------------
__global__ __launch_bounds__(256) void esrc_edst(
    const float* __restrict__ hp,
    const float* __restrict__ a_src,
    const float* __restrict__ a_dst,
    float* __restrict__ es, float* __restrict__ ed,
    unsigned short* __restrict__ hppk,          // pack dst (do_pack=1)
    float* __restrict__ h2w, const float* __restrict__ b2,  // optional init
    int N, int do_pack)
{
  __shared__ float sa[256], sd[256];
  int t = threadIdx.x;
  sa[t] = a_src[t]; sd[t] = a_dst[t];
  __syncthreads();
  int idx = blockIdx.x * 256 + t;
  if (h2w != nullptr && idx < N_W * 32) h2w[idx] = b2[idx & 31];
  if (idx >= N * 8) return;
  int n = idx >> 3, h = idx & 7;
  const float* hpp = hp + (size_t)n * 256 + h * 32;
  const float* ap = sa + h * 32;
  const float* dp = sd + h * 32;
  float s = 0.f, d = 0.f;
  float hv[32];
#pragma unroll
  for (int o = 0; o < 32; ++o) { hv[o] = hpp[o]; s += hv[o] * ap[o]; d += hv[o] * dp[o]; }
  es[h * N + n] = s; ed[h * N + n] = d;
  if (do_pack) {
    // B-fragment pack for pv1: element (k=n, col=o), head h
    unsigned short* dst = hppk + (size_t)h * (N_P * 32)
                        + (size_t)((n >> 5) * 4 + ((n >> 3) & 3)) * 256 + (n & 7);
#pragma unroll
    for (int o = 0; o < 32; ++o) dst[o * 8] = f2bf(hv[o]);
  }
}

// ---------------- attention softmax: one block per (head,row), bitmask adjacency ----------------
__global__ __launch_bounds__(256) void attn_softmax(
    const float* __restrict__ es, const float* __restrict__ ed,
    const unsigned long long* __restrict__ bm, int bstride,
    float* __restrict__ attn,
    int N)
{
  int h = blockIdx.x, n = blockIdx.y;
  int t = threadIdx.x, lane = t & 63, wid = t >> 6;
  __shared__ float red[4];
  float esv = es[h * N + n];
  const float* edh = ed + (size_t)h * N;
  const unsigned long long* brow = bm + (size_t)n * bstride;
  float v[9];
  float lmax = -3e38f;
#pragma unroll
  for (int i = 0; i < 9; ++i) {
    int m = i * 256 + t;
    float x = -3e38f;
    if (m < N) {
      float e = esv + edh[m];
      e = (e >= 0.f) ? e : 0.2f * e;
      x = ((brow[m >> 6] >> (m & 63)) & 1ULL) ? e : -1e9f;
    }
    v[i] = x; lmax = fmaxf(lmax, x);
  }
  lmax = waveMax(lmax);
  if (lane == 0) red[wid] = lmax;
  __syncthreads();
  float gmax = fmaxf(fmaxf(red[0], red[1]), fmaxf(red[2], red[3]));
  __syncthreads();
  float lsum = 0.f;
#pragma unroll
  for (int i = 0; i < 9; ++i) {
    int m = i * 256 + t;
    if (m < N) { float p = __expf(v[i] - gmax); v[i] = p; lsum += p; }
  }
  lsum = waveSum(lsum);
  if (lane == 0) red[wid] = lsum;
  __syncthreads();
  float inv = 1.f / (red[0] + red[1] + red[2] + red[3]);
  float* out = attn + ((size_t)h * N + n) * N;
#pragma unroll
  for (int i = 0; i < 9; ++i) {
    int m = i * 256 + t;
    if (m < N) out[m] = v[i] * inv;
  }
}

// ---------------- PV1 via bf16 MFMA, K-split in-block, fused bias+elu ----------------
// grid (64, 8): 32 attn rows per block, head = blockIdx.y.
__global__ __launch_bounds__(256) void pv1_mfma(
    const float* __restrict__ attn,         // [8][2048][2048] f32
    const unsigned short* __restrict__ hppk,// [8][2048*32] packed bf16
    const float* __restrict__ bias,         // [32]
    float* __restrict__ h1wp)               // rows 89.. : [(89+n)*256 + h*32 + c]
{
  __shared__ float red[2][16][33];
  int t = threadIdx.x, w = t >> 6, lane = t & 63;
  int col = lane & 15, quad = lane >> 4;
  int kh = w >> 1, rh = (w & 1) * 16;
  int h = blockIdx.y;
  int row0 = blockIdx.x * 32;
  int rowA = row0 + rh + col;
  const float* arow = attn + ((size_t)h * N_P + rowA) * N_P + kh * 1024;
  const unsigned short* wb0 = hppk + (size_t)h * (N_P * 32) + (size_t)kh * 32768;
  float4v acc0 = {0.f, 0.f, 0.f, 0.f}, acc1 = {0.f, 0.f, 0.f, 0.f};
#pragma unroll 4
  for (int kk = 0; kk < 1024; kk += 32) {
    short8 a = cvt8(arow + kk + quad * 8);
    const unsigned short* wb = wb0 + ((size_t)((kk >> 5) * 4 + quad) * 32 + col) * 8;
    short8 b0 = *(const short8*)(wb);
    short8 b1 = *(const short8*)(wb + 128);
    acc0 = __builtin_amdgcn_mfma_f32_16x16x32_bf16(a, b0, acc0, 0, 0, 0);
    acc1 = __builtin_amdgcn_mfma_f32_16x16x32_bf16(a, b1, acc1, 0, 0, 0);
  }
  if (kh == 1) {
#pragma unroll
    for (int r = 0; r < 4; ++r) {
      red[w & 1][quad * 4 + r][col] = acc0[r];
      red[w & 1][quad * 4 + r][16 + col] = acc1[r];
    }
  }
  __syncthreads();
  if (kh == 0) {
    int rbase = row0 + rh + quad * 4;
#pragma unroll
    for (int r = 0; r < 4; ++r) {
      float v0 = acc0[r] + red[w & 1][quad * 4 + r][col] + bias[col];
      float v1 = acc1[r] + red[w & 1][quad * 4 + r][16 + col] + bias[16 + col];
      v0 = (v0 > 0.f) ? v0 : expm1f(v0);
      v1 = (v1 > 0.f) ? v1 : expm1f(v1);
      float* dst = h1wp + (size_t)(N_W + rbase + r) * 256 + h * 32;
      dst[col] = v0; dst[16 + col] = v1;
    }
  }
}

// ---------------- PV for GAT2 word rows (h2w pre-initialized with bias) ----------------
__global__ __launch_bounds__(256) void pv2(
    const float* __restrict__ attn,
    const float* __restrict__ hp,
    float* __restrict__ h2w)
{
  int n = blockIdx.x, h = blockIdx.y;
  int t = threadIdx.x, g = t >> 5, o = t & 31;
  const float* arow = attn + ((size_t)h * N_ALLC + n) * N_ALLC;
  float acc = 0.f;
  for (int m = g; m < N_ALLC; m += 8) acc += arow[m] * hp[(size_t)m * 256 + h * 32 + o];
  __shared__ float pv[8][33];
  pv[g][o] = acc;
  __syncthreads();
  if (t < 32) {
    float s = 0.f;
#pragma unroll
    for (int gg = 0; gg < 8; ++gg) s += pv[gg][t];
    atomicAdd(&h2w[n * 32 + t], s * 0.125f);
  }
}

// ---------------- x: head matmul + concat + row-normalize (full-256-thread dot) ----------------
__global__ __launch_bounds__(256) void xnorm_kernel(
    const float* __restrict__ uwa,
    const float* __restrict__ h2w,
    float* __restrict__ xout)
{
  __shared__ float urow[4][320];
  __shared__ float sh2w[N_W * 32];
  __shared__ float px[4][2][32];
  __shared__ float xh[4][33];
  __shared__ float inv[4];
  int t = threadIdx.x;
  int b0 = blockIdx.x * 4;
  for (int i = t; i < N_W * 32; i += 256) sh2w[i] = h2w[i];
  for (int idx = t; idx < 4 * 313; idx += 256) {
    int r = idx / 313, j = idx - r * 313;
    urow[r][j] = uwa[(size_t)(b0 + r) * 313 + j];
  }
  __syncthreads();
  {
    int r = t >> 6, q = (t >> 5) & 1, o = t & 31;
    float s = 0.f;
    int i0 = q * 45, i1 = q ? N_W : 45;
    for (int i = i0; i < i1; ++i) s += urow[r][i] * sh2w[i * 32 + o];
    px[r][q][o] = s;
  }
  __syncthreads();
  if (t < 128) {
    int r = t >> 5, o = t & 31;
    xh[r][o] = px[r][0][o] + px[r][1][o];
  }
  __syncthreads();
  int lane = t & 63, w = t >> 6;
  float ls = 0.f;
  for (int c = lane; c < 256; c += 64) {
    float v = (c < 32) ? xh[w][c] : urow[w][89 + c - 32];
    ls += v;
  }
  ls = waveSum(ls);
  if (lane == 0) inv[w] = 1.f / ls;
  __syncthreads();
  for (int idx = t; idx < 1024; idx += 256) {
    int r = idx >> 8, c = idx & 255;
    float v = (c < 32) ? xh[r][c] : urow[r][89 + c - 32];
    xout[(size_t)(b0 + r) * 256 + c] = v * inv[r];
  }
}

// ---------------- fused o1|o2 -> o12bf (bf16 row-major [B][256]) ----------------
// grid (BQ/64, 2): y==0 -> o1 = x@Ws1+bs1 (cols 0..127); y==1 -> o2 = sent@Ws2+bs2 (cols 128..255)
__global__ __launch_bounds__(256) void o12_fused(
    const float* __restrict__ x,
    const float* __restrict__ sent,
    const unsigned short* __restrict__ ws1pk,
    const unsigned short* __restrict__ ws2pk,
    const float* __restrict__ bs1,
    const float* __restrict__ bs2,
    unsigned short* __restrict__ o12bf)
{
  int t = threadIdx.x, w = t >> 6, lane = t & 63;
  int col = lane & 15, quad = lane >> 4;
  int rowA = blockIdx.x * 64 + w * 16 + col;
  int half = blockIdx.y;
  const float* A = half ? (sent + (size_t)rowA * E2C) : (x + (size_t)rowA * 256);
  const unsigned short* wpk = half ? ws2pk : ws1pk;
  const float* bias = half ? bs2 : bs1;
  int K = half ? E2C : 256;
  float4v acc[8];
#pragma unroll
  for (int i = 0; i < 8; ++i) acc[i] = (float4v){0.f, 0.f, 0.f, 0.f};
#pragma unroll 4
  for (int k0 = 0; k0 < K; k0 += 32) {
    short8 a = cvt8(A + k0 + quad * 8);
    const unsigned short* wb = wpk + ((size_t)((k0 >> 5) * 4 + quad) * 128 + col) * 8;
#pragma unroll
    for (int nt = 0; nt < 8; ++nt)
      acc[nt] = __builtin_amdgcn_mfma_f32_16x16x32_bf16(a, *(const short8*)(wb + nt * 128), acc[nt], 0, 0, 0);
  }
  int rbase = blockIdx.x * 64 + w * 16 + quad * 4;
  int cb = half * 128;
#pragma unroll
  for (int nt = 0; nt < 8; ++nt) {
    int c = nt * 16 + col;
    float bv = bias[c];
#pragma unroll
    for (int r = 0; r < 4; ++r)
      o12bf[(size_t)(rbase + r) * 256 + cb + c] = f2bf(acc[nt][r] + bv);
  }
}

// ---------------- fused tail: o1n, o2n, t=relu(o12@Wfa+bfa), xtemp=t@Wfb+bfb ----------------
__global__ __launch_bounds__(256) void tail_fused(
    const unsigned short* __restrict__ o12bf,
    const unsigned short* __restrict__ wf1pk,   // K=128, N=64
    const unsigned short* __restrict__ wfapk,   // K=256, N=128
    const float* __restrict__ bf1,
    const float* __restrict__ bfa,
    const float* __restrict__ Wfb,              // [128][5]
    const float* __restrict__ bfb,              // [5]
    float* __restrict__ o1n, float* __restrict__ o2n, float* __restrict__ xt)
{
  __shared__ float sWfb[640];
  int t = threadIdx.x;
  for (int i = t; i < 640; i += 256) sWfb[i] = Wfb[i];
  __syncthreads();
  int w = t >> 6, lane = t & 63;
  int col = lane & 15, quad = lane >> 4;
  int rowA = blockIdx.x * 64 + w * 16 + col;
  const unsigned short* ar = o12bf + (size_t)rowA * 256;
  float4v aT[8], a1[4], a2[4];
#pragma unroll
  for (int i = 0; i < 8; ++i) aT[i] = (float4v){0.f, 0.f, 0.f, 0.f};
#pragma unroll
  for (int i = 0; i < 4; ++i) { a1[i] = (float4v){0.f, 0.f, 0.f, 0.f}; a2[i] = (float4v){0.f, 0.f, 0.f, 0.f}; }
#pragma unroll
  for (int k0 = 0; k0 < 128; k0 += 32) {
    short8 a = *(const short8*)(ar + k0 + quad * 8);
    const unsigned short* wbT = wfapk + ((size_t)((k0 >> 5) * 4 + quad) * 128 + col) * 8;
    const unsigned short* wb1 = wf1pk + ((size_t)((k0 >> 5) * 4 + quad) * 64 + col) * 8;
#pragma unroll
    for (int nt = 0; nt < 8; ++nt)
      aT[nt] = __builtin_amdgcn_mfma_f32_16x16x32_bf16(a, *(const short8*)(wbT + nt * 128), aT[nt], 0, 0, 0);
#pragma unroll
    for (int nt = 0; nt < 4; ++nt)
      a1[nt] = __builtin_amdgcn_mfma_f32_16x16x32_bf16(a, *(const short8*)(wb1 + nt * 128), a1[nt], 0, 0, 0);
  }
#pragma unroll
  for (int k0 = 128; k0 < 256; k0 += 32) {
    short8 a = *(const short8*)(ar + k0 + quad * 8);
    const unsigned short* wbT = wfapk + ((size_t)((k0 >> 5) * 4 + quad) * 128 + col) * 8;
    const unsigned short* wb1 = wf1pk + ((size_t)(((k0 - 128) >> 5) * 4 + quad) * 64 + col) * 8;
#pragma unroll
    for (int nt = 0; nt < 8; ++nt)
      aT[nt] = __builtin_amdgcn_mfma_f32_16x16x32_bf16(a, *(const short8*)(wbT + nt * 128), aT[nt], 0, 0, 0);
#pragma unroll
    for (int nt = 0; nt < 4; ++nt)
      a2[nt] = __builtin_amdgcn_mfma_f32_16x16x32_bf16(a, *(const short8*)(wb1 + nt * 128), a2[nt], 0, 0, 0);
  }
  int rbase = blockIdx.x * 64 + w * 16 + quad * 4;
#pragma unroll
  for (int nt = 0; nt < 4; ++nt) {
    int c = nt * 16 + col;
    float b1v = bf1[c];
#pragma unroll
    for (int r = 0; r < 4; ++r) {
      o1n[(size_t)(rbase + r) * 64 + c] = a1[nt][r] + b1v;
      o2n[(size_t)(rbase + r) * 64 + c] = a2[nt][r] + b1v;
    }
  }
  float xp[4][5] = {};
#pragma unroll
  for (int nt = 0; nt < 8; ++nt) {
    int c = nt * 16 + col;
    float bav = bfa[c];
#pragma unroll
    for (int r = 0; r < 4; ++r) {
      float tv = fmaxf(aT[nt][r] + bav, 0.f);
#pragma unroll
      for (int q = 0; q < 5; ++q) xp[r][q] += tv * sWfb[c * 5 + q];
    }
  }
#pragma unroll
  for (int m = 1; m <= 8; m <<= 1) {
#pragma unroll
    for (int r = 0; r < 4; ++r)
#pragma unroll
      for (int q = 0; q < 5; ++q) xp[r][q] += __shfl_xor(xp[r][q], m, 64);
  }
  if (col == 0) {
#pragma unroll
    for (int r = 0; r < 4; ++r)
#pragma unroll
      for (int q = 0; q < 5; ++q) xt[(size_t)(rbase + r) * 5 + q] = xp[r][q] + bfb[q];
  }
}

extern "C" void kernel_launch(void* const* d_in, const int* in_sizes, int n_in,
                              void* d_out, int out_size, void* d_ws, size_t ws_size,
                              hipStream_t stream)
{
  const float* pf   = (const float*)d_in[0];
  const float* wf   = (const float*)d_in[1];
  const int*   adj1 = (const int*)d_in[2];
  const int*   adj2 = (const int*)d_in[3];
  const float* uwa  = (const float*)d_in[4];
  const float* sent = (const float*)d_in[5];
  const float* w1   = (const float*)d_in[6];
  const float* as1  = (const float*)d_in[7];
  const float* ad1  = (const float*)d_in[8];
  const float* b1   = (const float*)d_in[9];
  const float* w2   = (const float*)d_in[10];
  const float* as2  = (const float*)d_in[11];
  const float* ad2  = (const float*)d_in[12];
  const float* b2   = (const float*)d_in[13];
  const float* Ws1  = (const float*)d_in[14];
  const float* bs1  = (const float*)d_in[15];
  const float* Ws2  = (const float*)d_in[16];
  const float* bs2  = (const float*)d_in[17];
  const float* Wf1  = (const float*)d_in[18];
  const float* bf1  = (const float*)d_in[19];
  const float* Wfa  = (const float*)d_in[20];
  const float* bfa  = (const float*)d_in[21];
  const float* Wfb  = (const float*)d_in[22];
  const float* bfb  = (const float*)d_in[23];

  float* ws = (float*)d_ws;
  float* wrm1 = ws;                                   // 65536
  float* wrm2 = wrm1 + 65536;                         // 65536
  float* hp1  = wrm2 + 65536;                         // 2048*256
  float* hp2  = hp1 + (size_t)N_P * 256;              // 2137*256
  float* es1v = hp2 + (size_t)N_ALLC * 256;           // 16384
  float* ed1v = es1v + 8 * N_P;                       // 16384
  float* es2v = ed1v + 8 * N_P;                       // 17096 (pad 17152)
  float* ed2v = es2v + 17152;                         // 17096 (pad 17152)
  float* h1wp = ed2v + 17152;                         // 2137*256
  float* h2w  = h1wp + (size_t)N_ALLC * 256;          // 2848 (pad 2880)
  unsigned long long* bm1 = (unsigned long long*)(h2w + 2880);  // 2048*32 u64
  unsigned long long* bm2 = bm1 + (size_t)2048 * 32;            // 2137*34 u64 (pad 72704)
  unsigned short* o12bf = (unsigned short*)(bm2 + 72704);       // BQ*256 ushorts
  unsigned short* hp1pk = o12bf + (size_t)BQ * 256;             // 8*2048*32
  unsigned short* ws1pk = hp1pk + 8 * N_P * 32;                 // 256*128
  unsigned short* ws2pk = ws1pk + 256 * 128;                    // 768*128
  unsigned short* wf1pk = ws2pk + 768 * 128;                    // 128*64
  unsigned short* wfapk = wf1pk + 128 * 64;                     // 256*128

  float* out = (float*)d_out;
  float* out_o1n = out;                                   // [B][64]
  float* out_o2n = out + (size_t)BQ * 64;                 // [B][64]
  float* out_xt  = out + (size_t)BQ * 128;                // [B][5]
  float* out_app = out_xt + (size_t)BQ * 5;               // [8][2048][2048]
  float* out_awp = out_app + (size_t)8 * N_P * N_P;       // [8][2137][2137]
  float* out_x   = out_awp + (size_t)8 * N_ALLC * N_ALLC; // [B][256]

  // 1. all repacks + word copy + adjacency bitmasks
  repack_all<<<1797, 256, 0, stream>>>(w1, wrm1, w2, wrm2, Ws1, ws1pk, Ws2, ws2pk,
                                       Wf1, wf1pk, Wfa, wfapk, wf, h1wp,
                                       adj1, bm1, adj2, bm2);
  // 2. hp1 = pern_feature @ W1rm
  gemm_f32<<<dim3(32, 4), 256, 0, stream>>>(pf, 256, wrm1, 256, hp1, 256, N_P, 256, 256);
  // 3. e_src/e_dst GAT1 + bf16 pack of hp1
  esrc_edst<<<(N_P * 8 + 255) / 256, 256, 0, stream>>>(hp1, as1, ad1, es1v, ed1v,
                                                       hp1pk, nullptr, nullptr, N_P, 1);
  // 4. attn softmax GAT1 -> out_app
  attn_softmax<<<dim3(8, N_P), 256, 0, stream>>>(es1v, ed1v, bm1, 32, out_app, N_P);
  // 5. PV1 (bf16 MFMA) + bias + elu -> h1wp rows 89..
  pv1_mfma<<<dim3(64, 8), 256, 0, stream>>>(out_app, hp1pk, b1, h1wp);
  // 6. hp2 = h1wp @ W2rm
  gemm_f32<<<dim3(34, 4), 256, 0, stream>>>(h1wp, 256, wrm2, 256, hp2, 256, N_ALLC, 256, 256);
  // 7. e_src/e_dst GAT2 (+ h2w bias init)
  esrc_edst<<<(N_ALLC * 8 + 255) / 256, 256, 0, stream>>>(hp2, as2, ad2, es2v, ed2v,
                                                          nullptr, h2w, b2, N_ALLC, 0);
  // 8. attn softmax GAT2 -> out_awp
  attn_softmax<<<dim3(8, N_ALLC), 256, 0, stream>>>(es2v, ed2v, bm2, 34, out_awp, N_ALLC);
  // 9. PV2 word rows -> h2w (atomic mean)
  pv2<<<dim3(N_W, 8), 256, 0, stream>>>(out_awp, hp2, h2w);
  // 10. x = normalize(cat(uwa[:, :89]@h2w, uwa[:, 89:])) -> out_x
  xnorm_kernel<<<BQ / 4, 256, 0, stream>>>(uwa, h2w, out_x);
  // 11. o12bf = bf16(cat(x@Ws1+bs1, sent@Ws2+bs2))
  o12_fused<<<dim3(BQ / 64, 2), 256, 0, stream>>>(out_x, sent, ws1pk, ws2pk, bs1, bs2, o12bf);
  // 12. o1n, o2n, xtemp
  tail_fused<<<BQ / 64, 256, 0, stream>>>(o12bf, wf1pk, wfapk, bf1, bfa, Wfb, bfb,
                                          out_o1n, out_o2n, out_xt);
}